// Round 2
// baseline (11.421 us; speedup 1.0000x reference)
//
#include <hip/hip_runtime.h>
#include <hip/hip_bf16.h>

// out[b] = sum_{i=0}^{31} w[i] * x[b]^i  == Horner, 31 FMA/element.
// Memory-bound: 16.8 MB in + 16.8 MB out -> ~5.3 us floor @ 6.3 TB/s.
// Structure: exact-fit grid, 2 float4 per thread loaded back-to-back
// (two coalesced streams, 2 outstanding loads/lane, 8 independent FMA
// chains/thread for full VALU issue efficiency). No grid-stride loop.

#define DIM 32

__global__ __launch_bounds__(256) void poly_horner_kernel(
    const float* __restrict__ x,
    const float* __restrict__ w,
    float* __restrict__ out,
    int n4)  // number of float4 elements
{
    // Coefficients: constant indices + uniform address -> s_load (SGPR),
    // hoisted once per wave.
    float c[DIM];
#pragma unroll
    for (int i = 0; i < DIM; ++i) c[i] = w[i];

    const float4* __restrict__ x4 = reinterpret_cast<const float4*>(x);
    float4* __restrict__ out4 = reinterpret_cast<float4*>(out);

    const int nthreads = gridDim.x * blockDim.x;
    const int tid = blockIdx.x * blockDim.x + threadIdx.x;

    const int i0 = tid;             // stream 0
    const int i1 = tid + nthreads;  // stream 1 (coalesced, second half)

    // Issue both loads back-to-back before any compute.
    float4 v0, v1;
    bool ok0 = (i0 < n4);
    bool ok1 = (i1 < n4);
    if (ok0) v0 = x4[i0];
    if (ok1) v1 = x4[i1];

    float4 r0, r1;
    r0.x = r0.y = r0.z = r0.w = c[DIM - 1];
    r1.x = r1.y = r1.z = r1.w = c[DIM - 1];
#pragma unroll
    for (int k = DIM - 2; k >= 0; --k) {
        r0.x = fmaf(r0.x, v0.x, c[k]);
        r0.y = fmaf(r0.y, v0.y, c[k]);
        r0.z = fmaf(r0.z, v0.z, c[k]);
        r0.w = fmaf(r0.w, v0.w, c[k]);
        r1.x = fmaf(r1.x, v1.x, c[k]);
        r1.y = fmaf(r1.y, v1.y, c[k]);
        r1.z = fmaf(r1.z, v1.z, c[k]);
        r1.w = fmaf(r1.w, v1.w, c[k]);
    }
    if (ok0) out4[i0] = r0;
    if (ok1) out4[i1] = r1;
}

extern "C" void kernel_launch(void* const* d_in, const int* in_sizes, int n_in,
                              void* d_out, int out_size, void* d_ws, size_t ws_size,
                              hipStream_t stream) {
    const float* x = (const float*)d_in[0];
    const float* w = (const float*)d_in[1];
    float* out = (float*)d_out;

    int n = in_sizes[0];          // 4194304
    int n4 = n / 4;               // 1048576 float4 elements

    const int block = 256;
    const int per_thread = 2;     // float4s per thread
    int grid = (n4 + block * per_thread - 1) / (block * per_thread);  // 2048

    poly_horner_kernel<<<grid, block, 0, stream>>>(x, w, out, n4);
}

// Round 3
// 11.356 us; speedup vs baseline: 1.0058x; 1.0058x over previous
//
#include <hip/hip_runtime.h>
#include <hip/hip_bf16.h>

// out[b] = sum_{i=0}^{31} w[i] * x[b]^i  == Horner, 31 FMA/element.
// Memory-bound: 16.8 MB in + 16.8 MB out -> ~5.3 us floor @ 6.3 TB/s.
// Round-3 discriminator: 4 coalesced float4 streams per thread (64 B
// in flight per lane), all loads issued before any compute. If this is
// again ~11.3 us, the floor is per-replay overhead, not the kernel.

#define DIM 32
#define PT 4  // float4s per thread

__global__ __launch_bounds__(256) void poly_horner_kernel(
    const float* __restrict__ x,
    const float* __restrict__ w,
    float* __restrict__ out,
    int n4)
{
    // Coefficients: uniform address, constant indices -> scalar loads.
    float c[DIM];
#pragma unroll
    for (int i = 0; i < DIM; ++i) c[i] = w[i];

    const float4* __restrict__ x4 = reinterpret_cast<const float4*>(x);
    float4* __restrict__ out4 = reinterpret_cast<float4*>(out);

    const int nthreads = gridDim.x * blockDim.x;
    const int tid = blockIdx.x * blockDim.x + threadIdx.x;

    // PT coalesced streams; exact-fit grid so no bounds checks needed
    // (n4 == nthreads * PT by construction in kernel_launch).
    float4 v[PT];
#pragma unroll
    for (int s = 0; s < PT; ++s) v[s] = x4[tid + s * nthreads];

    float4 r[PT];
#pragma unroll
    for (int s = 0; s < PT; ++s)
        r[s].x = r[s].y = r[s].z = r[s].w = c[DIM - 1];

#pragma unroll
    for (int k = DIM - 2; k >= 0; --k) {
#pragma unroll
        for (int s = 0; s < PT; ++s) {
            r[s].x = fmaf(r[s].x, v[s].x, c[k]);
            r[s].y = fmaf(r[s].y, v[s].y, c[k]);
            r[s].z = fmaf(r[s].z, v[s].z, c[k]);
            r[s].w = fmaf(r[s].w, v[s].w, c[k]);
        }
    }

#pragma unroll
    for (int s = 0; s < PT; ++s) out4[tid + s * nthreads] = r[s];
}

extern "C" void kernel_launch(void* const* d_in, const int* in_sizes, int n_in,
                              void* d_out, int out_size, void* d_ws, size_t ws_size,
                              hipStream_t stream) {
    const float* x = (const float*)d_in[0];
    const float* w = (const float*)d_in[1];
    float* out = (float*)d_out;

    int n = in_sizes[0];          // 4194304
    int n4 = n / 4;               // 1048576 float4 elements

    const int block = 256;
    int grid = n4 / (block * PT); // 1024 — exact fit (BATCH = 2^22)

    poly_horner_kernel<<<grid, block, 0, stream>>>(x, w, out, n4);
}